// Round 4
// baseline (1750.106 us; speedup 1.0000x reference)
//
#include <hip/hip_runtime.h>

// ---------------------------------------------------------------------------
// 2-layer GCN:  out = GCNConv2( relu(GCNConv1(x)) )
// GCNConv: h = x@W; deg[v] = indeg(v)+1 (self-loop); dinv = rsqrt(deg);
//          out[d] = sum_{e:(s->d)} dinv[s]*dinv[d]*h[s] + dinv[d]^2*h[d] + b
// edge_index arrives on device as int32 (harness converts int64 -> int).
// Indices are clamped defensively: an OOB atomic can core-dump the process
// and wedge the bench container; a clamp turns that into a visible absmax
// failure instead.
// ---------------------------------------------------------------------------

#define TPB 256

__device__ __forceinline__ int clampi(int v, int n) {
    return v < 0 ? 0 : (v >= n ? n - 1 : v);
}

// --- degree count (int atomics), dst-based -------------------------------
__global__ void k_deg(const int* __restrict__ dst, int E, int n,
                      int* __restrict__ cnt) {
    int i = blockIdx.x * blockDim.x + threadIdx.x;
    int stride = gridDim.x * blockDim.x;
    for (; i < E; i += stride) {
        atomicAdd(&cnt[clampi(dst[i], n)], 1);
    }
}

// --- dinv = rsqrt(cnt + 1), in place (int -> float) ----------------------
__global__ void k_dinv(int n, float* __restrict__ buf) {
    int i = blockIdx.x * blockDim.x + threadIdx.x;
    int stride = gridDim.x * blockDim.x;
    const int* ci = (const int*)buf;
    for (; i < n; i += stride) {
        int c = ci[i];
        buf[i] = rsqrtf((float)(c + 1));
    }
}

// --- h1 = x @ W1   (x: n x 128, W1: 128 x 16) ----------------------------
__global__ void k_mm1(const float* __restrict__ x, const float* __restrict__ W,
                      int n, float* __restrict__ h) {
    __shared__ float Ws[128 * 16];
    for (int i = threadIdx.x; i < 128 * 16; i += blockDim.x) Ws[i] = W[i];
    __syncthreads();
    int i = blockIdx.x * blockDim.x + threadIdx.x;
    int stride = gridDim.x * blockDim.x;
    for (; i < n; i += stride) {
        const float4* xr = (const float4*)(x + (size_t)i * 128);
        float acc[16];
#pragma unroll
        for (int hh = 0; hh < 16; ++hh) acc[hh] = 0.f;
#pragma unroll
        for (int j = 0; j < 32; ++j) {
            float4 v = xr[j];
            const float* w0 = &Ws[(4 * j) * 16];
#pragma unroll
            for (int hh = 0; hh < 16; ++hh)
                acc[hh] += v.x * w0[hh] + v.y * w0[16 + hh] +
                           v.z * w0[32 + hh] + v.w * w0[48 + hh];
        }
        float4* o = (float4*)(h + (size_t)i * 16);
#pragma unroll
        for (int j = 0; j < 4; ++j)
            o[j] = make_float4(acc[4 * j], acc[4 * j + 1], acc[4 * j + 2],
                               acc[4 * j + 3]);
    }
}

// --- h2 = relu_out1 @ W2   (h: n x 16, W2: 16 x 32) ----------------------
__global__ void k_mm2(const float* __restrict__ h, const float* __restrict__ W,
                      int n, float* __restrict__ o) {
    __shared__ float Ws[16 * 32];
    for (int i = threadIdx.x; i < 16 * 32; i += blockDim.x) Ws[i] = W[i];
    __syncthreads();
    int i = blockIdx.x * blockDim.x + threadIdx.x;
    int stride = gridDim.x * blockDim.x;
    for (; i < n; i += stride) {
        const float4* hr = (const float4*)(h + (size_t)i * 16);
        float acc[32];
#pragma unroll
        for (int c = 0; c < 32; ++c) acc[c] = 0.f;
#pragma unroll
        for (int j = 0; j < 4; ++j) {
            float4 v = hr[j];
            const float* w0 = &Ws[(4 * j) * 32];
#pragma unroll
            for (int c = 0; c < 32; ++c)
                acc[c] += v.x * w0[c] + v.y * w0[32 + c] + v.z * w0[64 + c] +
                          v.w * w0[96 + c];
        }
        float4* ot = (float4*)(o + (size_t)i * 32);
#pragma unroll
        for (int j = 0; j < 8; ++j)
            ot[j] = make_float4(acc[4 * j], acc[4 * j + 1], acc[4 * j + 2],
                                acc[4 * j + 3]);
    }
}

// --- edge scatter: agg[d*C+ch] += dinv[s]*dinv[d]*h[s*C+ch] --------------
// one thread per (edge, channel); C = 1<<LOGC. stride must be multiple of C.
template <int LOGC>
__global__ void k_agg(const int* __restrict__ src, const int* __restrict__ dst,
                      const float* __restrict__ dinv,
                      const float* __restrict__ h, float* __restrict__ agg,
                      int n, long long total) {
    const int C = 1 << LOGC;
    long long i = (long long)blockIdx.x * blockDim.x + threadIdx.x;
    long long stride = (long long)gridDim.x * blockDim.x;
    for (; i < total; i += stride) {
        long long e = i >> LOGC;
        int ch = (int)(i & (C - 1));
        int s = clampi(src[e], n);
        int d = clampi(dst[e], n);
        float nrm = dinv[s] * dinv[d];
        atomicAdd(&agg[(size_t)d * C + ch], nrm * h[(size_t)s * C + ch]);
    }
}

// --- finalize: out = agg + dinv^2 * hself + bias  (+relu) ----------------
template <int LOGC, bool RELU>
__global__ void k_fin(const float* __restrict__ agg,
                      const float* __restrict__ hself,
                      const float* __restrict__ dinv,
                      const float* __restrict__ bias, float* __restrict__ out,
                      long long total) {
    const int C = 1 << LOGC;
    long long i = (long long)blockIdx.x * blockDim.x + threadIdx.x;
    long long stride = (long long)gridDim.x * blockDim.x;
    for (; i < total; i += stride) {
        int v = (int)(i >> LOGC);
        int ch = (int)(i & (C - 1));
        float dv = dinv[v];
        float val = agg[i] + dv * dv * hself[i] + bias[ch];
        if (RELU) val = fmaxf(val, 0.f);
        out[i] = val;
    }
}

static inline int capped_blocks(long long total, int cap) {
    long long b = (total + TPB - 1) / TPB;
    return (int)(b < cap ? b : cap);
}

extern "C" void kernel_launch(void* const* d_in, const int* in_sizes, int n_in,
                              void* d_out, int out_size, void* d_ws,
                              size_t ws_size, hipStream_t stream) {
    const float* x = (const float*)d_in[0];
    const int* ei = (const int*)d_in[1];
    const float* W1 = (const float*)d_in[2];
    const float* b1 = (const float*)d_in[3];
    const float* W2 = (const float*)d_in[4];
    const float* b2 = (const float*)d_in[5];
    float* out = (float*)d_out;

    const int n = in_sizes[0] / 128;  // 200000 nodes
    const int E = in_sizes[1] / 2;    // 6400000 edges
    const int* src = ei;
    const int* dst = ei + E;

    // workspace layout (all f32):
    //  dinv: n  | buf1: n*16 (h1/relu1) | buf2: n*16 (agg1) | buf3: n*32 (h2)
    char* ws = (char*)d_ws;
    float* dinv = (float*)ws;
    float* buf1 = (float*)(ws + (size_t)n * 4);
    float* buf2 = (float*)(ws + (size_t)n * 4 + (size_t)n * 64);
    float* buf3 = (float*)(ws + (size_t)n * 4 + (size_t)n * 128);

    // --- degree / dinv ---
    hipMemsetAsync(dinv, 0, (size_t)n * 4, stream);
    k_deg<<<capped_blocks(E, 8192), TPB, 0, stream>>>(dst, E, n, (int*)dinv);
    k_dinv<<<(n + TPB - 1) / TPB, TPB, 0, stream>>>(n, dinv);

    // --- layer 1 ---
    k_mm1<<<(n + TPB - 1) / TPB, TPB, 0, stream>>>(x, W1, n, buf1);
    hipMemsetAsync(buf2, 0, (size_t)n * 64, stream);
    {
        long long total = (long long)E * 16;
        k_agg<4><<<capped_blocks(total, 8192), TPB, 0, stream>>>(
            src, dst, dinv, buf1, buf2, n, total);
        long long tfin = (long long)n * 16;
        k_fin<4, true><<<capped_blocks(tfin, 8192), TPB, 0, stream>>>(
            buf2, buf1, dinv, b1, buf1, tfin);
    }

    // --- layer 2 ---
    hipMemsetAsync(out, 0, (size_t)out_size * 4, stream);
    {
        k_mm2<<<(n + TPB - 1) / TPB, TPB, 0, stream>>>(buf1, W2, n, buf3);
        long long total = (long long)E * 32;
        k_agg<5><<<capped_blocks(total, 8192), TPB, 0, stream>>>(
            src, dst, dinv, buf3, out, n, total);
        long long tfin = (long long)n * 32;
        k_fin<5, false><<<capped_blocks(tfin, 8192), TPB, 0, stream>>>(
            out, buf3, dinv, b2, out, tfin);
    }
}

// Round 5
// 1111.480 us; speedup vs baseline: 1.5746x; 1.5746x over previous
//
#include <hip/hip_runtime.h>

// ---------------------------------------------------------------------------
// 2-layer GCN via device-built CSR (no f32 atomics):
//   deg -> scan -> scatter(adj)        CSR build, int atomics only
//   h1 = x @ W1                        (n x 16)
//   z1 = relu(D^-1/2 A D^-1/2 h1 + b1) CSR gather, C=16
//   pre = D^-1/2 A D^-1/2 z1           CSR gather, C=16  (aggregate-first!)
//   out = pre @ W2 + b2                (n x 32)  -- linearity of aggregation
// edge_index arrives as int32. Indices clamped defensively (OOB atomics can
// wedge the container; clamp -> visible absmax failure instead).
// ---------------------------------------------------------------------------

#define TPB 256

__device__ __forceinline__ int clampi(int v, int n) {
    return v < 0 ? 0 : (v >= n ? n - 1 : v);
}

// --- degree count (int atomics), dst-based -------------------------------
__global__ void k_deg(const int* __restrict__ dst, int E, int n,
                      int* __restrict__ cnt) {
    int i = blockIdx.x * blockDim.x + threadIdx.x;
    int stride = gridDim.x * blockDim.x;
    for (; i < E; i += stride) atomicAdd(&cnt[clampi(dst[i], n)], 1);
}

// --- scan pass 1: per-block (1024 elems) sums ----------------------------
__global__ void scan_p1(const int* __restrict__ cnt, int n,
                        int* __restrict__ bsum) {
    __shared__ int s[256];
    int base = blockIdx.x * 1024;
    int t = threadIdx.x;
    int a = 0;
#pragma unroll
    for (int k = 0; k < 4; ++k) {
        int idx = base + 4 * t + k;
        if (idx < n) a += cnt[idx];
    }
    s[t] = a;
    __syncthreads();
    for (int off = 128; off > 0; off >>= 1) {
        if (t < off) s[t] += s[t + off];
        __syncthreads();
    }
    if (t == 0) bsum[blockIdx.x] = s[0];
}

// --- scan pass 2: exclusive scan of block sums (nb <= 256 fast path) -----
__global__ void scan_p2(int* __restrict__ bsum, int nb) {
    __shared__ int s[256];
    int t = threadIdx.x;
    if (nb <= 256) {
        s[t] = (t < nb) ? bsum[t] : 0;
        __syncthreads();
        if (t == 0) {
            int run = 0;
            for (int i = 0; i < nb; ++i) {
                int v = s[i];
                s[i] = run;
                run += v;
            }
        }
        __syncthreads();
        if (t < nb) bsum[t] = s[t];
    } else if (t == 0) {  // robust fallback
        int run = 0;
        for (int i = 0; i < nb; ++i) {
            int v = bsum[i];
            bsum[i] = run;
            run += v;
        }
    }
}

// --- scan pass 3: per-block exclusive scan + offset -> rp; also dinv -----
// rp[v] = exclusive prefix sum of cnt (row start). dinv[v]=rsqrt(cnt[v]+1)
// written in-place over cnt (each idx touched by exactly one thread).
__global__ void scan_p3(int* __restrict__ cnt, int n,
                        const int* __restrict__ bsum, int* __restrict__ rp) {
    __shared__ int s[256];
    int base = blockIdx.x * 1024;
    int t = threadIdx.x;
    int loc[4];
    int a = 0;
#pragma unroll
    for (int k = 0; k < 4; ++k) {
        int idx = base + 4 * t + k;
        loc[k] = (idx < n) ? cnt[idx] : 0;
        a += loc[k];
    }
    s[t] = a;
    __syncthreads();
    for (int off = 1; off < 256; off <<= 1) {
        int v = (t >= off) ? s[t - off] : 0;
        __syncthreads();
        s[t] += v;
        __syncthreads();
    }
    int off0 = bsum[blockIdx.x] + (s[t] - a);
    float* dinv = (float*)cnt;
#pragma unroll
    for (int k = 0; k < 4; ++k) {
        int idx = base + 4 * t + k;
        if (idx < n) {
            rp[idx] = off0;
            off0 += loc[k];
            dinv[idx] = rsqrtf((float)(loc[k] + 1));
        }
    }
}

// --- scatter: adj[rp[d]++] = s  (rp becomes inclusive ends) --------------
__global__ void k_scatter(const int* __restrict__ src,
                          const int* __restrict__ dst, int E, int n,
                          int* __restrict__ rp, int* __restrict__ adj) {
    int i = blockIdx.x * blockDim.x + threadIdx.x;
    int stride = gridDim.x * blockDim.x;
    for (; i < E; i += stride) {
        int s = clampi(src[i], n);
        int d = clampi(dst[i], n);
        int pos = atomicAdd(&rp[d], 1);
        adj[pos] = s;
    }
}

// --- h1 = x @ W1   (x: n x 128, W1: 128 x 16) ----------------------------
__global__ void k_mm1(const float* __restrict__ x, const float* __restrict__ W,
                      int n, float* __restrict__ h) {
    __shared__ float Ws[128 * 16];
    for (int i = threadIdx.x; i < 128 * 16; i += blockDim.x) Ws[i] = W[i];
    __syncthreads();
    int i = blockIdx.x * blockDim.x + threadIdx.x;
    int stride = gridDim.x * blockDim.x;
    for (; i < n; i += stride) {
        const float4* xr = (const float4*)(x + (size_t)i * 128);
        float acc[16];
#pragma unroll
        for (int hh = 0; hh < 16; ++hh) acc[hh] = 0.f;
#pragma unroll
        for (int j = 0; j < 32; ++j) {
            float4 v = xr[j];
            const float* w0 = &Ws[(4 * j) * 16];
#pragma unroll
            for (int hh = 0; hh < 16; ++hh)
                acc[hh] += v.x * w0[hh] + v.y * w0[16 + hh] +
                           v.z * w0[32 + hh] + v.w * w0[48 + hh];
        }
        float4* o = (float4*)(h + (size_t)i * 16);
#pragma unroll
        for (int j = 0; j < 4; ++j)
            o[j] = make_float4(acc[4 * j], acc[4 * j + 1], acc[4 * j + 2],
                               acc[4 * j + 3]);
    }
}

// --- CSR gather + finalize, C=16:
//   o[v,j] = dinv[v]*sum_k dinv[adj[k]]*h[adj[k],j] + dinv[v]^2*h[v,j] (+b,relu)
// thread = (node, channel j); rp holds inclusive ends (start = rp[v-1]).
template <bool RELU, bool BIAS>
__global__ void k_gather16(const int* __restrict__ rp,
                           const int* __restrict__ adj,
                           const float* __restrict__ dinv,
                           const float* __restrict__ h,
                           const float* __restrict__ bias,
                           float* __restrict__ o, int n) {
    long long total = (long long)n * 16;
    long long i = (long long)blockIdx.x * blockDim.x + threadIdx.x;
    long long stride = (long long)gridDim.x * blockDim.x;
    for (; i < total; i += stride) {
        int v = (int)(i >> 4);
        int j = (int)(i & 15);
        int start = (v == 0) ? 0 : rp[v - 1];
        int end = rp[v];
        float acc0 = 0.f, acc1 = 0.f;
        int k = start;
        for (; k + 1 < end; k += 2) {
            int s0 = adj[k], s1 = adj[k + 1];
            acc0 += dinv[s0] * h[(size_t)s0 * 16 + j];
            acc1 += dinv[s1] * h[(size_t)s1 * 16 + j];
        }
        if (k < end) {
            int s0 = adj[k];
            acc0 += dinv[s0] * h[(size_t)s0 * 16 + j];
        }
        float dv = dinv[v];
        float val = dv * (acc0 + acc1) + dv * dv * h[i];
        if (BIAS) val += bias[j];
        if (RELU) val = fmaxf(val, 0.f);
        o[i] = val;
    }
}

// --- out = pre @ W2 + b2   (pre: n x 16, W2: 16 x 32) --------------------
__global__ void k_out(const float* __restrict__ pre,
                      const float* __restrict__ W2,
                      const float* __restrict__ b2, float* __restrict__ out,
                      int n) {
    __shared__ float Ws[16 * 32];
    for (int i = threadIdx.x; i < 16 * 32; i += blockDim.x) Ws[i] = W2[i];
    __syncthreads();
    long long total = (long long)n * 32;
    long long i = (long long)blockIdx.x * blockDim.x + threadIdx.x;
    long long stride = (long long)gridDim.x * blockDim.x;
    for (; i < total; i += stride) {
        int v = (int)(i >> 5);
        int c = (int)(i & 31);
        const float* pr = pre + (size_t)v * 16;
        float acc = b2[c];
#pragma unroll
        for (int j = 0; j < 16; ++j) acc += pr[j] * Ws[j * 32 + c];
        out[i] = acc;
    }
}

static inline int capped_blocks(long long total, int cap) {
    long long b = (total + TPB - 1) / TPB;
    return (int)(b < cap ? b : cap);
}

extern "C" void kernel_launch(void* const* d_in, const int* in_sizes, int n_in,
                              void* d_out, int out_size, void* d_ws,
                              size_t ws_size, hipStream_t stream) {
    const float* x = (const float*)d_in[0];
    const int* ei = (const int*)d_in[1];
    const float* W1 = (const float*)d_in[2];
    const float* b1 = (const float*)d_in[3];
    const float* W2 = (const float*)d_in[4];
    const float* b2 = (const float*)d_in[5];
    float* out = (float*)d_out;

    const int n = in_sizes[0] / 128;  // 200000 nodes
    const int E = in_sizes[1] / 2;    // 6400000 edges
    const int* src = ei;
    const int* dst = ei + E;

    // workspace (f32/int32 elements):
    //  cnt/dinv: n | rp: n | adj: E | bufA: n*16 (h1 -> pre) | bufB: n*16 (z1)
    char* ws = (char*)d_ws;
    int* cnt = (int*)ws;                                   // -> dinv (float)
    int* rp = (int*)(ws + (size_t)n * 4);
    int* adj = (int*)(ws + (size_t)n * 8);
    float* bufA = (float*)(ws + (size_t)n * 8 + (size_t)E * 4);
    float* bufB = bufA + (size_t)n * 16;
    float* dinv = (float*)cnt;

    const int nb = (n + 1023) / 1024;  // scan blocks (196 for n=200k)
    // bsum lives in spare space after bufB
    int* bsum = (int*)(bufB + (size_t)n * 16);

    // --- CSR build + dinv ---
    hipMemsetAsync(cnt, 0, (size_t)n * 4, stream);
    k_deg<<<capped_blocks(E, 8192), TPB, 0, stream>>>(dst, E, n, cnt);
    scan_p1<<<nb, 256, 0, stream>>>(cnt, n, bsum);
    scan_p2<<<1, 256, 0, stream>>>(bsum, nb);
    scan_p3<<<nb, 256, 0, stream>>>(cnt, n, bsum, rp);  // rp=row starts; cnt->dinv
    k_scatter<<<capped_blocks(E, 8192), TPB, 0, stream>>>(src, dst, E, n, rp,
                                                          adj);
    // rp now holds inclusive row ends.

    // --- layer 1: h1 = x@W1 ; z1 = relu(agg(h1) + b1) ---
    k_mm1<<<(n + TPB - 1) / TPB, TPB, 0, stream>>>(x, W1, n, bufA);
    k_gather16<true, true><<<capped_blocks((long long)n * 16, 8192), TPB, 0,
                             stream>>>(rp, adj, dinv, bufA, b1, bufB, n);

    // --- layer 2: pre = agg(z1) ; out = pre@W2 + b2 ---
    k_gather16<false, false><<<capped_blocks((long long)n * 16, 8192), TPB, 0,
                               stream>>>(rp, adj, dinv, bufB, nullptr, bufA, n);
    k_out<<<capped_blocks((long long)n * 32, 8192), TPB, 0, stream>>>(
        bufA, W2, b2, out, n);
}